// Round 5
// baseline (379.983 us; speedup 1.0000x reference)
//
#include <hip/hip_runtime.h>
#include <math.h>

#define HEADS 4
#define CH 256
#define HC 1024
#define NEG_SLOPE 0.2f
#define EPSQ 1e-16f

typedef __attribute__((ext_vector_type(8))) short bf16x8;
typedef __attribute__((ext_vector_type(4))) float f32x4;

static inline int cdiv(int a, int b) { return (a + b - 1) / b; }

__device__ __forceinline__ unsigned short f2bf(float f) {
  unsigned u = __float_as_uint(f);
  u += 0x7FFFu + ((u >> 16) & 1u);  // RNE
  return (unsigned short)(u >> 16);
}
__device__ __forceinline__ float bf2f(unsigned short s) {
  return __uint_as_float(((unsigned)s) << 16);
}
__device__ __forceinline__ float bf_lo(unsigned p) {  // low bf16 of packed pair
  return __uint_as_float(p << 16);
}
__device__ __forceinline__ float bf_hi(unsigned p) {  // high bf16 of packed pair
  return __uint_as_float(p & 0xFFFF0000u);
}
__device__ __forceinline__ void gload_lds16(const void* g, void* l) {
  __builtin_amdgcn_global_load_lds((const __attribute__((address_space(1))) void*)g,
                                   (__attribute__((address_space(3))) void*)l, 16, 0, 0);
}

// ---------------- CSR build ----------------
__global__ void k_count(const int* __restrict__ ei, int E, int ET, int* __restrict__ cnt) {
  int e = blockIdx.x * blockDim.x + threadIdx.x;
  if (e >= ET) return;
  int d = (e < E) ? ei[E + e] : (e - E);
  atomicAdd(&cnt[d], 1);
}

// wave-shfl scan: 2-3 barriers per 1024 chunk instead of ~20
__global__ __launch_bounds__(1024) void k_scan(const int* __restrict__ counts,
                                               int* __restrict__ offsets, int n) {
  __shared__ int wsum[16];
  __shared__ int carry_s;
  int lane = threadIdx.x & 63, wv = threadIdx.x >> 6;
  if (threadIdx.x == 0) carry_s = 0;
  __syncthreads();
  for (int base = 0; base < n; base += 1024) {
    int i = base + threadIdx.x;
    int orig = (i < n) ? counts[i] : 0;
    int v = orig;
#pragma unroll
    for (int off = 1; off < 64; off <<= 1) {
      int t = __shfl_up(v, off);
      if (lane >= off) v += t;
    }
    if (lane == 63) wsum[wv] = v;
    __syncthreads();
    int carry = carry_s;
    int wpre = 0;
#pragma unroll
    for (int w = 0; w < 16; w++) wpre += (w < wv) ? wsum[w] : 0;
    int incl = v + wpre;  // inclusive within chunk
    if (i < n) offsets[i] = carry + incl - orig;  // exclusive
    __syncthreads();
    if (threadIdx.x == 1023) carry_s = carry + incl;  // wv=15,lane=63 -> chunk total
    __syncthreads();
  }
  if (threadIdx.x == 0) offsets[n] = carry_s;
}

__global__ void k_fill(const int* __restrict__ ei, int E, int ET,
                       const int* __restrict__ offsets, int* __restrict__ cursor,
                       int* __restrict__ esrc) {
  int e = blockIdx.x * blockDim.x + threadIdx.x;
  if (e >= ET) return;
  int s = (e < E) ? ei[e] : (e - E);
  int d = (e < E) ? ei[E + e] : (e - E);
  int pos = offsets[d] + atomicAdd(&cursor[d], 1);
  esrc[pos] = s;
}

// ---------------- W transpose + cast: Wt[n][k] = bf16(W[k][n]) ----------------
__global__ __launch_bounds__(256) void k_transpose_w(const float* __restrict__ W,
                                                     unsigned short* __restrict__ Wt, int K) {
  __shared__ float tile[32][33];
  int tx = threadIdx.x & 31, ty = threadIdx.x >> 5;  // 8 rows of 32
  int k0 = blockIdx.x * 32, n0 = blockIdx.y * 32;
#pragma unroll
  for (int r = ty; r < 32; r += 8) tile[r][tx] = W[(size_t)(k0 + r) * HC + n0 + tx];
  __syncthreads();
#pragma unroll
  for (int r = ty; r < 32; r += 8)
    Wt[(size_t)(n0 + r) * K + k0 + tx] = f2bf(tile[tx][r]);
}

// ---------------- cast fp32 -> bf16 (8 per thread) ----------------
__global__ void k_cast_bf16(const float* __restrict__ in, unsigned short* __restrict__ out,
                            int n) {
  int i = (blockIdx.x * blockDim.x + threadIdx.x) * 8;
  if (i >= n) return;
  float4 a = *(const float4*)&in[i];
  float4 b = *(const float4*)&in[i + 4];
  ushort4 lo = make_ushort4(f2bf(a.x), f2bf(a.y), f2bf(a.z), f2bf(a.w));
  ushort4 hi = make_ushort4(f2bf(b.x), f2bf(b.y), f2bf(b.z), f2bf(b.w));
  *(ushort4*)&out[i] = lo;
  *(ushort4*)&out[i + 4] = hi;
}

// ---------------- bf16 MFMA GEMM: hb[M,1024](bf16) = A[M,K] @ Wt[1024,K]^T ----------------
__global__ __launch_bounds__(256) void k_gemm_mfma(const unsigned short* __restrict__ A,
                                                   const unsigned short* __restrict__ Bt,
                                                   unsigned short* __restrict__ hb, int M,
                                                   int K) {
  __shared__ unsigned short sA[2][128 * 32];
  __shared__ unsigned short sB[2][128 * 32];
  int t = threadIdx.x;
  int lane = t & 63, wv = t >> 6;
  int wr = wv >> 1, wc = wv & 1;
  int row0 = blockIdx.x * 128, col0 = blockIdx.y * 128;
  int l15 = lane & 15, l4 = lane >> 4;

  f32x4 acc[4][4] = {};

  auto stage = [&](unsigned short* sdst, const unsigned short* g, int grow0, int rowmax,
                   int k0) {
#pragma unroll
    for (int q = 0; q < 2; ++q) {
      int r = grow0 + q * 64 + (t >> 2);
      if (r > rowmax) r = rowmax;
      const unsigned short* gp = g + (size_t)r * K + k0 + (t & 3) * 8;
      gload_lds16(gp, sdst + q * 2048 + t * 8);
    }
  };

  int KT = K / 32;
  stage(sA[0], A, row0, M - 1, 0);
  stage(sB[0], Bt, col0, HC - 1, 0);
  int cur = 0;
  for (int kt = 0; kt < KT; ++kt) {
    __syncthreads();
    if (kt + 1 < KT) {
      stage(sA[cur ^ 1], A, row0, M - 1, (kt + 1) * 32);
      stage(sB[cur ^ 1], Bt, col0, HC - 1, (kt + 1) * 32);
    }
    bf16x8 af[4], bfr[4];
#pragma unroll
    for (int i = 0; i < 4; i++)
      af[i] = *(bf16x8*)&sA[cur][(wr * 64 + i * 16 + l15) * 32 + l4 * 8];
#pragma unroll
    for (int j = 0; j < 4; j++)
      bfr[j] = *(bf16x8*)&sB[cur][(wc * 64 + j * 16 + l15) * 32 + l4 * 8];
#pragma unroll
    for (int i = 0; i < 4; i++)
#pragma unroll
      for (int j = 0; j < 4; j++)
        acc[i][j] = __builtin_amdgcn_mfma_f32_16x16x32_bf16(af[i], bfr[j], acc[i][j], 0, 0, 0);
    cur ^= 1;
  }
#pragma unroll
  for (int i = 0; i < 4; i++) {
#pragma unroll
    for (int j = 0; j < 4; j++) {
      int col = col0 + wc * 64 + j * 16 + l15;
#pragma unroll
      for (int r = 0; r < 4; r++) {
        int row = row0 + wr * 64 + i * 16 + l4 * 4 + r;
        if (row < M) hb[(size_t)row * HC + col] = f2bf(acc[i][j][r]);
      }
    }
  }
}

// ---------------- per-node logits (bf16 h) ----------------
__global__ __launch_bounds__(256) void k_logits(const unsigned short* __restrict__ h,
                                                const float* __restrict__ as_,
                                                const float* __restrict__ ad_,
                                                float* __restrict__ es,
                                                float* __restrict__ ed) {
  int n = blockIdx.x;
  int w = threadIdx.x >> 6, l = threadIdx.x & 63;
  ushort4 hv = *(const ushort4*)&h[(size_t)n * HC + w * CH + l * 4];
  const float4 s4 = *(const float4*)&as_[w * CH + l * 4];
  const float4 d4 = *(const float4*)&ad_[w * CH + l * 4];
  float h0 = bf2f(hv.x), h1 = bf2f(hv.y), h2 = bf2f(hv.z), h3 = bf2f(hv.w);
  float ds = h0 * s4.x + h1 * s4.y + h2 * s4.z + h3 * s4.w;
  float dd = h0 * d4.x + h1 * d4.y + h2 * d4.z + h3 * d4.w;
#pragma unroll
  for (int off = 32; off; off >>= 1) {
    ds += __shfl_xor(ds, off);
    dd += __shfl_xor(dd, off);
  }
  if (l == 0) {
    es[n * HEADS + w] = ds;
    ed[n * HEADS + w] = dd;
  }
}

// ---------------- XCD-sliced aggregation ----------------
// slice c = blockIdx.x & 7 (aligns with round-robin block->XCD mapping).
// Slice c owns output channels [c*32, c*32+32) for ALL heads: it gathers
// h columns {head*256 + c*32 + [0,32)} -> per-XCD working set 4*64B*N = 2.5MB
// (L2-resident). Lane = head(lane>>4) x ch-pair((lane&15)*2); 1 dword/edge/lane.
// alpha computed inline (softmax shift-invariant, no max pass); denom folded.
__global__ __launch_bounds__(256) void k_aggregate(const unsigned short* __restrict__ hfeat,
                                                   const float* __restrict__ es,
                                                   const float* __restrict__ ed,
                                                   const int* __restrict__ offsets,
                                                   const int* __restrict__ esrc,
                                                   const float* __restrict__ bias,
                                                   float* __restrict__ xout,
                                                   unsigned short* __restrict__ xout_bf,
                                                   int N) {
  int c = blockIdx.x & 7;
  int n = (blockIdx.x >> 3) * 4 + (threadIdx.x >> 6);
  if (n >= N) return;
  int lane = threadIdx.x & 63;
  int head = lane >> 4;
  int chp = (lane & 15) * 2;                 // even channel within slice
  int hcol = head * 256 + c * 32 + chp;      // column in h
  float edv = ed[n * 4 + head];
  float acc0 = 0.f, acc1 = 0.f, sum_a = 0.f;
  int k0 = offsets[n], k1 = offsets[n + 1];
  int k = k0;
  for (; k + 1 < k1; k += 2) {
    int s0 = esrc[k], s1 = esrc[k + 1];
    float e0 = es[s0 * 4 + head] + edv;
    float e1 = es[s1 * 4 + head] + edv;
    unsigned p0 = *(const unsigned*)&hfeat[((size_t)s0 << 10) + hcol];
    unsigned p1 = *(const unsigned*)&hfeat[((size_t)s1 << 10) + hcol];
    e0 = e0 > 0.f ? e0 : NEG_SLOPE * e0;
    e1 = e1 > 0.f ? e1 : NEG_SLOPE * e1;
    float a0 = __expf(e0), a1 = __expf(e1);
    acc0 += a0 * bf_lo(p0) + a1 * bf_lo(p1);
    acc1 += a0 * bf_hi(p0) + a1 * bf_hi(p1);
    sum_a += a0 + a1;
  }
  if (k < k1) {
    int s0 = esrc[k];
    float e0 = es[s0 * 4 + head] + edv;
    unsigned p0 = *(const unsigned*)&hfeat[((size_t)s0 << 10) + hcol];
    e0 = e0 > 0.f ? e0 : NEG_SLOPE * e0;
    float a0 = __expf(e0);
    acc0 += a0 * bf_lo(p0);
    acc1 += a0 * bf_hi(p0);
    sum_a += a0;
  }
  float invh = 0.25f / (sum_a + EPSQ);  // per-head denom + head-mean, folded
  acc0 *= invh;
  acc1 *= invh;
  acc0 += __shfl_xor(acc0, 16);
  acc0 += __shfl_xor(acc0, 32);
  acc1 += __shfl_xor(acc1, 16);
  acc1 += __shfl_xor(acc1, 32);
  if (lane < 16) {
    int oc = c * 32 + chp;  // output channel
    float v0 = acc0 + bias[oc];
    float v1 = acc1 + bias[oc + 1];
    if (xout) *(float2*)&xout[(size_t)n * CH + oc] = make_float2(v0, v1);
    if (xout_bf) {
      ushort2 o;
      o.x = f2bf(v0);
      o.y = f2bf(v1);
      *(ushort2*)&xout_bf[(size_t)n * CH + oc] = o;
    }
  }
}

extern "C" void kernel_launch(void* const* d_in, const int* in_sizes, int n_in,
                              void* d_out, int out_size, void* d_ws, size_t ws_size,
                              hipStream_t stream) {
  const float* x = (const float*)d_in[0];
  const int* ei = (const int*)d_in[1];
  const float* W[3] = {(const float*)d_in[2], (const float*)d_in[6], (const float*)d_in[10]};
  const float* AS[3] = {(const float*)d_in[3], (const float*)d_in[7], (const float*)d_in[11]};
  const float* AD[3] = {(const float*)d_in[4], (const float*)d_in[8], (const float*)d_in[12]};
  const float* BI[3] = {(const float*)d_in[5], (const float*)d_in[9], (const float*)d_in[13]};
  const int N = in_sizes[0] / 512;
  const int E = in_sizes[1] / 2;
  const int ET = E + N;
  const int Kd[3] = {512, 256, 256};

  char* p = (char*)d_ws;
  auto alloc = [&](size_t bytes) {
    char* r = p;
    p += (bytes + 255) & ~(size_t)255;
    return (void*)r;
  };
  unsigned short* hb = (unsigned short*)alloc((size_t)N * HC * 2);
  unsigned short* axb = (unsigned short*)alloc((size_t)N * 512 * 2);
  unsigned short* actbf = (unsigned short*)alloc((size_t)N * CH * 2);
  unsigned short* Wt[3];
  for (int i = 0; i < 3; i++) Wt[i] = (unsigned short*)alloc((size_t)HC * Kd[i] * 2);
  float* es = (float*)alloc((size_t)N * HEADS * 4);
  float* ed = (float*)alloc((size_t)N * HEADS * 4);
  int* offsets = (int*)alloc((size_t)(N + 1) * 4);
  int* cursor = (int*)alloc((size_t)N * 4);
  int* esrc = (int*)alloc((size_t)ET * 4);

  // ---- CSR build (shared by all 3 layers) ----
  hipMemsetAsync(cursor, 0, (size_t)N * 4, stream);
  k_count<<<cdiv(ET, 256), 256, 0, stream>>>(ei, E, ET, cursor);
  k_scan<<<1, 1024, 0, stream>>>(cursor, offsets, N);
  hipMemsetAsync(cursor, 0, (size_t)N * 4, stream);
  k_fill<<<cdiv(ET, 256), 256, 0, stream>>>(ei, E, ET, offsets, cursor, esrc);

  // ---- weight transpose+cast, input cast ----
  for (int i = 0; i < 3; i++)
    k_transpose_w<<<dim3(Kd[i] / 32, HC / 32), 256, 0, stream>>>(W[i], Wt[i], Kd[i]);
  k_cast_bf16<<<cdiv(N * 512, 8 * 256), 256, 0, stream>>>(x, axb, N * 512);

  const unsigned short* ain = axb;
  int aggGrid = cdiv(N, 4) * 8;
  for (int layer = 0; layer < 3; ++layer) {
    int K = Kd[layer];
    k_gemm_mfma<<<dim3(cdiv(N, 128), HC / 128), 256, 0, stream>>>(ain, Wt[layer], hb, N, K);
    k_logits<<<N, 256, 0, stream>>>(hb, AS[layer], AD[layer], es, ed);
    if (layer < 2) {
      k_aggregate<<<aggGrid, 256, 0, stream>>>(hb, es, ed, offsets, esrc, BI[layer],
                                               (float*)nullptr, actbf, N);
    } else {
      k_aggregate<<<aggGrid, 256, 0, stream>>>(hb, es, ed, offsets, esrc, BI[layer],
                                               (float*)d_out, (unsigned short*)nullptr, N);
    }
    ain = actbf;
  }
}

// Round 6
// 358.208 us; speedup vs baseline: 1.0608x; 1.0608x over previous
//
#include <hip/hip_runtime.h>
#include <math.h>

#define HEADS 4
#define CH 256
#define HC 1024
#define NSLICE 8
#define NEG_SLOPE 0.2f
#define EPSQ 1e-16f

typedef __attribute__((ext_vector_type(8))) short bf16x8;
typedef __attribute__((ext_vector_type(4))) float f32x4;

static inline int cdiv(int a, int b) { return (a + b - 1) / b; }

__device__ __forceinline__ unsigned short f2bf(float f) {
  unsigned u = __float_as_uint(f);
  u += 0x7FFFu + ((u >> 16) & 1u);  // RNE
  return (unsigned short)(u >> 16);
}
__device__ __forceinline__ float bf2f(unsigned short s) {
  return __uint_as_float(((unsigned)s) << 16);
}
__device__ __forceinline__ float bf_lo(unsigned p) {
  return __uint_as_float(p << 16);
}
__device__ __forceinline__ float bf_hi(unsigned p) {
  return __uint_as_float(p & 0xFFFF0000u);
}
__device__ __forceinline__ void gload_lds16(const void* g, void* l) {
  __builtin_amdgcn_global_load_lds((const __attribute__((address_space(1))) void*)g,
                                   (__attribute__((address_space(3))) void*)l, 16, 0, 0);
}

// ---------------- CSR build ----------------
__global__ void k_count(const int* __restrict__ ei, int E, int ET, int* __restrict__ cnt) {
  int e = blockIdx.x * blockDim.x + threadIdx.x;
  if (e >= ET) return;
  int d = (e < E) ? ei[E + e] : (e - E);
  atomicAdd(&cnt[d], 1);
}

__global__ __launch_bounds__(1024) void k_scan(const int* __restrict__ counts,
                                               int* __restrict__ offsets, int n) {
  __shared__ int wsum[16];
  __shared__ int carry_s;
  int lane = threadIdx.x & 63, wv = threadIdx.x >> 6;
  if (threadIdx.x == 0) carry_s = 0;
  __syncthreads();
  for (int base = 0; base < n; base += 1024) {
    int i = base + threadIdx.x;
    int orig = (i < n) ? counts[i] : 0;
    int v = orig;
#pragma unroll
    for (int off = 1; off < 64; off <<= 1) {
      int t = __shfl_up(v, off);
      if (lane >= off) v += t;
    }
    if (lane == 63) wsum[wv] = v;
    __syncthreads();
    int carry = carry_s;
    int wpre = 0;
#pragma unroll
    for (int w = 0; w < 16; w++) wpre += (w < wv) ? wsum[w] : 0;
    int incl = v + wpre;
    if (i < n) offsets[i] = carry + incl - orig;
    __syncthreads();
    if (threadIdx.x == 1023) carry_s = carry + incl;
    __syncthreads();
  }
  if (threadIdx.x == 0) offsets[n] = carry_s;
}

__global__ void k_fill(const int* __restrict__ ei, int E, int ET,
                       const int* __restrict__ offsets, int* __restrict__ cursor,
                       int* __restrict__ esrc, int* __restrict__ edst) {
  int e = blockIdx.x * blockDim.x + threadIdx.x;
  if (e >= ET) return;
  int s = (e < E) ? ei[e] : (e - E);
  int d = (e < E) ? ei[E + e] : (e - E);
  int pos = offsets[d] + atomicAdd(&cursor[d], 1);
  esrc[pos] = s;
  edst[pos] = d;
}

// ---------------- W transpose + cast ----------------
__global__ __launch_bounds__(256) void k_transpose_w(const float* __restrict__ W,
                                                     unsigned short* __restrict__ Wt, int K) {
  __shared__ float tile[32][33];
  int tx = threadIdx.x & 31, ty = threadIdx.x >> 5;
  int k0 = blockIdx.x * 32, n0 = blockIdx.y * 32;
#pragma unroll
  for (int r = ty; r < 32; r += 8) tile[r][tx] = W[(size_t)(k0 + r) * HC + n0 + tx];
  __syncthreads();
#pragma unroll
  for (int r = ty; r < 32; r += 8)
    Wt[(size_t)(n0 + r) * K + k0 + tx] = f2bf(tile[tx][r]);
}

// ---------------- cast fp32 -> bf16 ----------------
__global__ void k_cast_bf16(const float* __restrict__ in, unsigned short* __restrict__ out,
                            int n) {
  int i = (blockIdx.x * blockDim.x + threadIdx.x) * 8;
  if (i >= n) return;
  float4 a = *(const float4*)&in[i];
  float4 b = *(const float4*)&in[i + 4];
  ushort4 lo = make_ushort4(f2bf(a.x), f2bf(a.y), f2bf(a.z), f2bf(a.w));
  ushort4 hi = make_ushort4(f2bf(b.x), f2bf(b.y), f2bf(b.z), f2bf(b.w));
  *(ushort4*)&out[i] = lo;
  *(ushort4*)&out[i + 4] = hi;
}

// ---------------- bf16 MFMA GEMM, epilogue writes slice-major hsl[c][n][128] ----
// hsl[c][n][head*32+j] = h[n][head*256 + c*32 + j]   (2 B elements, 256 B/node/slice)
__global__ __launch_bounds__(256) void k_gemm_mfma(const unsigned short* __restrict__ A,
                                                   const unsigned short* __restrict__ Bt,
                                                   unsigned short* __restrict__ hsl, int M,
                                                   int K) {
  __shared__ unsigned short sA[2][128 * 32];
  __shared__ unsigned short sB[2][128 * 32];
  int t = threadIdx.x;
  int lane = t & 63, wv = t >> 6;
  int wr = wv >> 1, wc = wv & 1;
  int row0 = blockIdx.x * 128, col0 = blockIdx.y * 128;
  int l15 = lane & 15, l4 = lane >> 4;

  f32x4 acc[4][4] = {};

  auto stage = [&](unsigned short* sdst, const unsigned short* g, int grow0, int rowmax,
                   int k0) {
#pragma unroll
    for (int q = 0; q < 2; ++q) {
      int r = grow0 + q * 64 + (t >> 2);
      if (r > rowmax) r = rowmax;
      const unsigned short* gp = g + (size_t)r * K + k0 + (t & 3) * 8;
      gload_lds16(gp, sdst + q * 2048 + t * 8);
    }
  };

  int KT = K / 32;
  stage(sA[0], A, row0, M - 1, 0);
  stage(sB[0], Bt, col0, HC - 1, 0);
  int cur = 0;
  for (int kt = 0; kt < KT; ++kt) {
    __syncthreads();
    if (kt + 1 < KT) {
      stage(sA[cur ^ 1], A, row0, M - 1, (kt + 1) * 32);
      stage(sB[cur ^ 1], Bt, col0, HC - 1, (kt + 1) * 32);
    }
    bf16x8 af[4], bfr[4];
#pragma unroll
    for (int i = 0; i < 4; i++)
      af[i] = *(bf16x8*)&sA[cur][(wr * 64 + i * 16 + l15) * 32 + l4 * 8];
#pragma unroll
    for (int j = 0; j < 4; j++)
      bfr[j] = *(bf16x8*)&sB[cur][(wc * 64 + j * 16 + l15) * 32 + l4 * 8];
#pragma unroll
    for (int i = 0; i < 4; i++)
#pragma unroll
      for (int j = 0; j < 4; j++)
        acc[i][j] = __builtin_amdgcn_mfma_f32_16x16x32_bf16(af[i], bfr[j], acc[i][j], 0, 0, 0);
    cur ^= 1;
  }
#pragma unroll
  for (int i = 0; i < 4; i++) {
#pragma unroll
    for (int j = 0; j < 4; j++) {
      int col = col0 + wc * 64 + j * 16 + l15;
      int head = col >> 8;
      int c = (col >> 5) & 7;
      int jj = col & 31;
      size_t sbase = ((size_t)c * M) * 128 + (head << 5) + jj;
#pragma unroll
      for (int r = 0; r < 4; r++) {
        int row = row0 + wr * 64 + i * 16 + l4 * 4 + r;
        if (row < M) hsl[sbase + (size_t)row * 128] = f2bf(acc[i][j][r]);
      }
    }
  }
}

// ---------------- per-node logits from slice-major hsl ----------------
__global__ __launch_bounds__(256) void k_logits(const unsigned short* __restrict__ hsl,
                                                const float* __restrict__ as_,
                                                const float* __restrict__ ad_,
                                                float* __restrict__ es, float* __restrict__ ed,
                                                int M) {
  __shared__ float lds_s[4][64];
  __shared__ float lds_d[4][64];
  int n = blockIdx.x;
  int t = threadIdx.x;
  int c = t >> 5, chunk = t & 31;
  int head = chunk >> 3, q = chunk * 4;  // q within [0,128), 4-aligned, same head
  ushort4 hv = *(const ushort4*)&hsl[((size_t)c * M + n) * 128 + q];
  int ch = head * 256 + c * 32 + (q & 31);
  float4 s4 = *(const float4*)&as_[ch];
  float4 d4 = *(const float4*)&ad_[ch];
  float h0 = bf2f(hv.x), h1 = bf2f(hv.y), h2 = bf2f(hv.z), h3 = bf2f(hv.w);
  float ds = h0 * s4.x + h1 * s4.y + h2 * s4.z + h3 * s4.w;
  float dd = h0 * d4.x + h1 * d4.y + h2 * d4.z + h3 * d4.w;
  int g = c * 8 + (chunk & 7);
  lds_s[head][g] = ds;
  lds_d[head][g] = dd;
  __syncthreads();
  int wv = t >> 6, l = t & 63;
  float vs = lds_s[wv][l];
  float vd = lds_d[wv][l];
#pragma unroll
  for (int off = 32; off; off >>= 1) {
    vs += __shfl_xor(vs, off);
    vd += __shfl_xor(vd, off);
  }
  if (l == 0) {
    es[n * HEADS + wv] = vs;
    ed[n * HEADS + wv] = vd;
  }
}

// ---------------- slot-ordered edge exp (no max: shift-invariant, bounded logits) --
__global__ void k_edge_exp(const int* __restrict__ esrc, const int* __restrict__ edst, int ET,
                           const float4* __restrict__ es4, const float4* __restrict__ ed4,
                           float4* __restrict__ exs4) {
  int k = blockIdx.x * blockDim.x + threadIdx.x;
  if (k >= ET) return;
  int s = esrc[k], d = edst[k];
  float4 a = es4[s], b = ed4[d];
  float v0 = a.x + b.x, v1 = a.y + b.y, v2 = a.z + b.z, v3 = a.w + b.w;
  v0 = v0 > 0.f ? v0 : NEG_SLOPE * v0;
  v1 = v1 > 0.f ? v1 : NEG_SLOPE * v1;
  v2 = v2 > 0.f ? v2 : NEG_SLOPE * v2;
  v3 = v3 > 0.f ? v3 : NEG_SLOPE * v3;
  exs4[k] = make_float4(__expf(v0), __expf(v1), __expf(v2), __expf(v3));
}

// ---------------- per-node inverse denom: inva[n][h] = 0.25/(sum_k alpha + eps) ---
__global__ __launch_bounds__(256) void k_denom(const float* __restrict__ exs,
                                               const int* __restrict__ offsets,
                                               float* __restrict__ inva, int N) {
  int lane = threadIdx.x & 63;
  int n = blockIdx.x * 4 + (threadIdx.x >> 6);
  if (n >= N) return;
  int sub = lane >> 2, h = lane & 3;  // lane = sub*4+h -> coalesced exs reads
  int k0 = offsets[n], k1 = offsets[n + 1];
  float sum = 0.f;
  for (int k = k0 + sub; k < k1; k += 16) sum += exs[k * 4 + h];
#pragma unroll
  for (int off = 4; off < 64; off <<= 1) sum += __shfl_xor(sum, off);
  if (lane < 4) inva[n * 4 + h] = 0.25f / (sum + EPSQ);
}

// ---------------- XCD-sliced aggregation over slice-major hsl ----------------
// slice c = blockIdx.x & 7 (round-robin block->XCD); slice table = M*256 B
// contiguous (2.5 MB, L2-resident). Per edge a wave reads one contiguous 256 B
// burst; all per-edge math (exp, denom) precomputed.
__global__ __launch_bounds__(256) void k_aggregate(const unsigned short* __restrict__ hsl,
                                                   const float* __restrict__ exs,
                                                   const float* __restrict__ inva,
                                                   const int* __restrict__ offsets,
                                                   const int* __restrict__ esrc,
                                                   const float* __restrict__ bias,
                                                   float* __restrict__ xout,
                                                   unsigned short* __restrict__ xout_bf,
                                                   int N) {
  int c = blockIdx.x & 7;
  int n = (blockIdx.x >> 3) * 4 + (threadIdx.x >> 6);
  if (n >= N) return;
  int lane = threadIdx.x & 63;
  int head = lane >> 4;
  int lane2 = lane * 2;  // q-pair within slice row
  const unsigned short* sl = hsl + (size_t)c * N * 128;
  float acc0 = 0.f, acc1 = 0.f;
  int k0 = offsets[n], k1 = offsets[n + 1];
  int k = k0;
  for (; k + 1 < k1; k += 2) {
    int s0 = esrc[k], s1 = esrc[k + 1];
    float a0 = exs[k * 4 + head];
    float a1 = exs[k * 4 + 4 + head];
    unsigned p0 = *(const unsigned*)&sl[(size_t)s0 * 128 + lane2];
    unsigned p1 = *(const unsigned*)&sl[(size_t)s1 * 128 + lane2];
    acc0 += a0 * bf_lo(p0) + a1 * bf_lo(p1);
    acc1 += a0 * bf_hi(p0) + a1 * bf_hi(p1);
  }
  if (k < k1) {
    int s0 = esrc[k];
    float a0 = exs[k * 4 + head];
    unsigned p0 = *(const unsigned*)&sl[(size_t)s0 * 128 + lane2];
    acc0 += a0 * bf_lo(p0);
    acc1 += a0 * bf_hi(p0);
  }
  float ia = inva[n * 4 + head];  // includes 0.25 head-mean
  acc0 *= ia;
  acc1 *= ia;
  acc0 += __shfl_xor(acc0, 16);
  acc0 += __shfl_xor(acc0, 32);
  acc1 += __shfl_xor(acc1, 16);
  acc1 += __shfl_xor(acc1, 32);
  if (lane < 16) {
    int oc = c * 32 + lane * 2;
    float v0 = acc0 + bias[oc];
    float v1 = acc1 + bias[oc + 1];
    if (xout) *(float2*)&xout[(size_t)n * CH + oc] = make_float2(v0, v1);
    if (xout_bf) {
      ushort2 o;
      o.x = f2bf(v0);
      o.y = f2bf(v1);
      *(ushort2*)&xout_bf[(size_t)n * CH + oc] = o;
    }
  }
}

extern "C" void kernel_launch(void* const* d_in, const int* in_sizes, int n_in,
                              void* d_out, int out_size, void* d_ws, size_t ws_size,
                              hipStream_t stream) {
  const float* x = (const float*)d_in[0];
  const int* ei = (const int*)d_in[1];
  const float* W[3] = {(const float*)d_in[2], (const float*)d_in[6], (const float*)d_in[10]};
  const float* AS[3] = {(const float*)d_in[3], (const float*)d_in[7], (const float*)d_in[11]};
  const float* AD[3] = {(const float*)d_in[4], (const float*)d_in[8], (const float*)d_in[12]};
  const float* BI[3] = {(const float*)d_in[5], (const float*)d_in[9], (const float*)d_in[13]};
  const int N = in_sizes[0] / 512;
  const int E = in_sizes[1] / 2;
  const int ET = E + N;
  const int Kd[3] = {512, 256, 256};

  char* p = (char*)d_ws;
  auto alloc = [&](size_t bytes) {
    char* r = p;
    p += (bytes + 255) & ~(size_t)255;
    return (void*)r;
  };
  unsigned short* hsl = (unsigned short*)alloc((size_t)NSLICE * N * 128 * 2);
  unsigned short* axb = (unsigned short*)alloc((size_t)N * 512 * 2);
  unsigned short* actbf = (unsigned short*)alloc((size_t)N * CH * 2);
  unsigned short* Wt[3];
  for (int i = 0; i < 3; i++) Wt[i] = (unsigned short*)alloc((size_t)HC * Kd[i] * 2);
  float* es = (float*)alloc((size_t)N * HEADS * 4);
  float* ed = (float*)alloc((size_t)N * HEADS * 4);
  float* exs = (float*)alloc((size_t)ET * HEADS * 4);
  float* inva = (float*)alloc((size_t)N * HEADS * 4);
  int* offsets = (int*)alloc((size_t)(N + 1) * 4);
  int* cursor = (int*)alloc((size_t)N * 4);
  int* esrc = (int*)alloc((size_t)ET * 4);
  int* edst = (int*)alloc((size_t)ET * 4);

  // ---- CSR build (shared by all 3 layers) ----
  hipMemsetAsync(cursor, 0, (size_t)N * 4, stream);
  k_count<<<cdiv(ET, 256), 256, 0, stream>>>(ei, E, ET, cursor);
  k_scan<<<1, 1024, 0, stream>>>(cursor, offsets, N);
  hipMemsetAsync(cursor, 0, (size_t)N * 4, stream);
  k_fill<<<cdiv(ET, 256), 256, 0, stream>>>(ei, E, ET, offsets, cursor, esrc, edst);

  // ---- weight transpose+cast, input cast ----
  for (int i = 0; i < 3; i++)
    k_transpose_w<<<dim3(Kd[i] / 32, HC / 32), 256, 0, stream>>>(W[i], Wt[i], Kd[i]);
  k_cast_bf16<<<cdiv(N * 512, 8 * 256), 256, 0, stream>>>(x, axb, N * 512);

  const unsigned short* ain = axb;
  int aggGrid = cdiv(N, 4) * 8;
  for (int layer = 0; layer < 3; ++layer) {
    int K = Kd[layer];
    k_gemm_mfma<<<dim3(cdiv(N, 128), HC / 128), 256, 0, stream>>>(ain, Wt[layer], hsl, N, K);
    k_logits<<<N, 256, 0, stream>>>(hsl, AS[layer], AD[layer], es, ed, N);
    k_edge_exp<<<cdiv(ET, 256), 256, 0, stream>>>(esrc, edst, ET, (const float4*)es,
                                                  (const float4*)ed, (float4*)exs);
    k_denom<<<cdiv(N, 4), 256, 0, stream>>>(exs, offsets, inva, N);
    if (layer < 2) {
      k_aggregate<<<aggGrid, 256, 0, stream>>>(hsl, exs, inva, offsets, esrc, BI[layer],
                                               (float*)nullptr, actbf, N);
    } else {
      k_aggregate<<<aggGrid, 256, 0, stream>>>(hsl, exs, inva, offsets, esrc, BI[layer],
                                               (float*)d_out, (unsigned short*)nullptr, N);
    }
    ain = actbf;
  }
}

// Round 7
// 323.935 us; speedup vs baseline: 1.1730x; 1.1058x over previous
//
#include <hip/hip_runtime.h>
#include <math.h>

#define HEADS 4
#define CH 256
#define HC 1024
#define NSLICE 8
#define NEG_SLOPE 0.2f
#define EPSQ 1e-16f

typedef __attribute__((ext_vector_type(8))) short bf16x8;
typedef __attribute__((ext_vector_type(4))) float f32x4;

static inline int cdiv(int a, int b) { return (a + b - 1) / b; }

__device__ __forceinline__ unsigned short f2bf(float f) {
  unsigned u = __float_as_uint(f);
  u += 0x7FFFu + ((u >> 16) & 1u);  // RNE
  return (unsigned short)(u >> 16);
}
__device__ __forceinline__ float bf2f(unsigned short s) {
  return __uint_as_float(((unsigned)s) << 16);
}
__device__ __forceinline__ float bf_lo(unsigned p) {
  return __uint_as_float(p << 16);
}
__device__ __forceinline__ float bf_hi(unsigned p) {
  return __uint_as_float(p & 0xFFFF0000u);
}
__device__ __forceinline__ void gload_lds16(const void* g, void* l) {
  __builtin_amdgcn_global_load_lds((const __attribute__((address_space(1))) void*)g,
                                   (__attribute__((address_space(3))) void*)l, 16, 0, 0);
}

// ---------------- CSR build ----------------
__global__ void k_count(const int* __restrict__ ei, int E, int ET, int* __restrict__ cnt) {
  int e = blockIdx.x * blockDim.x + threadIdx.x;
  if (e >= ET) return;
  int d = (e < E) ? ei[E + e] : (e - E);
  atomicAdd(&cnt[d], 1);
}

__global__ __launch_bounds__(1024) void k_scan(const int* __restrict__ counts,
                                               int* __restrict__ offsets, int n) {
  __shared__ int wsum[16];
  __shared__ int carry_s;
  int lane = threadIdx.x & 63, wv = threadIdx.x >> 6;
  if (threadIdx.x == 0) carry_s = 0;
  __syncthreads();
  for (int base = 0; base < n; base += 1024) {
    int i = base + threadIdx.x;
    int orig = (i < n) ? counts[i] : 0;
    int v = orig;
#pragma unroll
    for (int off = 1; off < 64; off <<= 1) {
      int t = __shfl_up(v, off);
      if (lane >= off) v += t;
    }
    if (lane == 63) wsum[wv] = v;
    __syncthreads();
    int carry = carry_s;
    int wpre = 0;
#pragma unroll
    for (int w = 0; w < 16; w++) wpre += (w < wv) ? wsum[w] : 0;
    int incl = v + wpre;
    if (i < n) offsets[i] = carry + incl - orig;
    __syncthreads();
    if (threadIdx.x == 1023) carry_s = carry + incl;
    __syncthreads();
  }
  if (threadIdx.x == 0) offsets[n] = carry_s;
}

__global__ void k_fill(const int* __restrict__ ei, int E, int ET,
                       const int* __restrict__ offsets, int* __restrict__ cursor,
                       int* __restrict__ esrc, int* __restrict__ edst) {
  int e = blockIdx.x * blockDim.x + threadIdx.x;
  if (e >= ET) return;
  int s = (e < E) ? ei[e] : (e - E);
  int d = (e < E) ? ei[E + e] : (e - E);
  int pos = offsets[d] + atomicAdd(&cursor[d], 1);
  esrc[pos] = s;
  edst[pos] = d;
}

// ---------------- W transpose + cast ----------------
__global__ __launch_bounds__(256) void k_transpose_w(const float* __restrict__ W,
                                                     unsigned short* __restrict__ Wt, int K) {
  __shared__ float tile[32][33];
  int tx = threadIdx.x & 31, ty = threadIdx.x >> 5;
  int k0 = blockIdx.x * 32, n0 = blockIdx.y * 32;
#pragma unroll
  for (int r = ty; r < 32; r += 8) tile[r][tx] = W[(size_t)(k0 + r) * HC + n0 + tx];
  __syncthreads();
#pragma unroll
  for (int r = ty; r < 32; r += 8)
    Wt[(size_t)(n0 + r) * K + k0 + tx] = f2bf(tile[tx][r]);
}

// ---------------- cast fp32 -> bf16 ----------------
__global__ void k_cast_bf16(const float* __restrict__ in, unsigned short* __restrict__ out,
                            int n) {
  int i = (blockIdx.x * blockDim.x + threadIdx.x) * 8;
  if (i >= n) return;
  float4 a = *(const float4*)&in[i];
  float4 b = *(const float4*)&in[i + 4];
  ushort4 lo = make_ushort4(f2bf(a.x), f2bf(a.y), f2bf(a.z), f2bf(a.w));
  ushort4 hi = make_ushort4(f2bf(b.x), f2bf(b.y), f2bf(b.z), f2bf(b.w));
  *(ushort4*)&out[i] = lo;
  *(ushort4*)&out[i + 4] = hi;
}

// ---------------- bf16 MFMA GEMM, epilogue writes slice-major hsl[c][n][128] ----
__global__ __launch_bounds__(256) void k_gemm_mfma(const unsigned short* __restrict__ A,
                                                   const unsigned short* __restrict__ Bt,
                                                   unsigned short* __restrict__ hsl, int M,
                                                   int K) {
  __shared__ unsigned short sA[2][128 * 32];
  __shared__ unsigned short sB[2][128 * 32];
  int t = threadIdx.x;
  int lane = t & 63, wv = t >> 6;
  int wr = wv >> 1, wc = wv & 1;
  int row0 = blockIdx.x * 128, col0 = blockIdx.y * 128;
  int l15 = lane & 15, l4 = lane >> 4;

  f32x4 acc[4][4] = {};

  auto stage = [&](unsigned short* sdst, const unsigned short* g, int grow0, int rowmax,
                   int k0) {
#pragma unroll
    for (int q = 0; q < 2; ++q) {
      int r = grow0 + q * 64 + (t >> 2);
      if (r > rowmax) r = rowmax;
      const unsigned short* gp = g + (size_t)r * K + k0 + (t & 3) * 8;
      gload_lds16(gp, sdst + q * 2048 + t * 8);
    }
  };

  int KT = K / 32;
  stage(sA[0], A, row0, M - 1, 0);
  stage(sB[0], Bt, col0, HC - 1, 0);
  int cur = 0;
  for (int kt = 0; kt < KT; ++kt) {
    __syncthreads();
    if (kt + 1 < KT) {
      stage(sA[cur ^ 1], A, row0, M - 1, (kt + 1) * 32);
      stage(sB[cur ^ 1], Bt, col0, HC - 1, (kt + 1) * 32);
    }
    bf16x8 af[4], bfr[4];
#pragma unroll
    for (int i = 0; i < 4; i++)
      af[i] = *(bf16x8*)&sA[cur][(wr * 64 + i * 16 + l15) * 32 + l4 * 8];
#pragma unroll
    for (int j = 0; j < 4; j++)
      bfr[j] = *(bf16x8*)&sB[cur][(wc * 64 + j * 16 + l15) * 32 + l4 * 8];
#pragma unroll
    for (int i = 0; i < 4; i++)
#pragma unroll
      for (int j = 0; j < 4; j++)
        acc[i][j] = __builtin_amdgcn_mfma_f32_16x16x32_bf16(af[i], bfr[j], acc[i][j], 0, 0, 0);
    cur ^= 1;
  }
#pragma unroll
  for (int i = 0; i < 4; i++) {
#pragma unroll
    for (int j = 0; j < 4; j++) {
      int col = col0 + wc * 64 + j * 16 + l15;
      int head = col >> 8;
      int c = (col >> 5) & 7;
      int jj = col & 31;
      size_t sbase = ((size_t)c * M) * 128 + (head << 5) + jj;
#pragma unroll
      for (int r = 0; r < 4; r++) {
        int row = row0 + wr * 64 + i * 16 + l4 * 4 + r;
        if (row < M) hsl[sbase + (size_t)row * 128] = f2bf(acc[i][j][r]);
      }
    }
  }
}

// ---------------- per-node logits from slice-major hsl ----------------
__global__ __launch_bounds__(256) void k_logits(const unsigned short* __restrict__ hsl,
                                                const float* __restrict__ as_,
                                                const float* __restrict__ ad_,
                                                float* __restrict__ es, float* __restrict__ ed,
                                                int M) {
  __shared__ float lds_s[4][64];
  __shared__ float lds_d[4][64];
  int n = blockIdx.x;
  int t = threadIdx.x;
  int c = t >> 5, chunk = t & 31;
  int head = chunk >> 3, q = chunk * 4;
  ushort4 hv = *(const ushort4*)&hsl[((size_t)c * M + n) * 128 + q];
  int ch = head * 256 + c * 32 + (q & 31);
  float4 s4 = *(const float4*)&as_[ch];
  float4 d4 = *(const float4*)&ad_[ch];
  float h0 = bf2f(hv.x), h1 = bf2f(hv.y), h2 = bf2f(hv.z), h3 = bf2f(hv.w);
  float ds = h0 * s4.x + h1 * s4.y + h2 * s4.z + h3 * s4.w;
  float dd = h0 * d4.x + h1 * d4.y + h2 * d4.z + h3 * d4.w;
  int g = c * 8 + (chunk & 7);
  lds_s[head][g] = ds;
  lds_d[head][g] = dd;
  __syncthreads();
  int wv = t >> 6, l = t & 63;
  float vs = lds_s[wv][l];
  float vd = lds_d[wv][l];
#pragma unroll
  for (int off = 32; off; off >>= 1) {
    vs += __shfl_xor(vs, off);
    vd += __shfl_xor(vd, off);
  }
  if (l == 0) {
    es[n * HEADS + wv] = vs;
    ed[n * HEADS + wv] = vd;
  }
}

// ---------------- slot-ordered edge exp ----------------
__global__ void k_edge_exp(const int* __restrict__ esrc, const int* __restrict__ edst, int ET,
                           const float4* __restrict__ es4, const float4* __restrict__ ed4,
                           float4* __restrict__ exs4) {
  int k = blockIdx.x * blockDim.x + threadIdx.x;
  if (k >= ET) return;
  int s = esrc[k], d = edst[k];
  float4 a = es4[s], b = ed4[d];
  float v0 = a.x + b.x, v1 = a.y + b.y, v2 = a.z + b.z, v3 = a.w + b.w;
  v0 = v0 > 0.f ? v0 : NEG_SLOPE * v0;
  v1 = v1 > 0.f ? v1 : NEG_SLOPE * v1;
  v2 = v2 > 0.f ? v2 : NEG_SLOPE * v2;
  v3 = v3 > 0.f ? v3 : NEG_SLOPE * v3;
  exs4[k] = make_float4(__expf(v0), __expf(v1), __expf(v2), __expf(v3));
}

// ---------------- per-node inverse denom ----------------
__global__ __launch_bounds__(256) void k_denom(const float* __restrict__ exs,
                                               const int* __restrict__ offsets,
                                               float* __restrict__ inva, int N) {
  int lane = threadIdx.x & 63;
  int n = blockIdx.x * 4 + (threadIdx.x >> 6);
  if (n >= N) return;
  int sub = lane >> 2, h = lane & 3;
  int k0 = offsets[n], k1 = offsets[n + 1];
  float sum = 0.f;
  for (int k = k0 + sub; k < k1; k += 16) sum += exs[k * 4 + h];
#pragma unroll
  for (int off = 4; off < 64; off <<= 1) sum += __shfl_xor(sum, off);
  if (lane < 4) inva[n * 4 + h] = 0.25f / (sum + EPSQ);
}

// ---------------- XCD-sliced aggregation, lean edge loop ----------------
// Per 16-edge chunk: lane i preloads esrc[slot(i&15)] and exs[slot(i&15)*4+(i>>4)]
// (one 64B + one 256B coalesced load). Per edge: s via readlane (SGPR -> saddr
// global_load), alpha via one bpermute shfl, 2 unpack + 2 FMA. 16 independent
// gathers in flight per chunk.
__global__ __launch_bounds__(256) void k_aggregate(const unsigned short* __restrict__ hsl,
                                                   const float* __restrict__ exs,
                                                   const float* __restrict__ inva,
                                                   const int* __restrict__ offsets,
                                                   const int* __restrict__ esrc,
                                                   const float* __restrict__ bias,
                                                   float* __restrict__ xout,
                                                   unsigned short* __restrict__ xout_bf,
                                                   int N) {
  int c = blockIdx.x & 7;
  int n = (blockIdx.x >> 3) * 4 + (threadIdx.x >> 6);
  if (n >= N) return;
  int lane = threadIdx.x & 63;
  int head = lane >> 4;
  int lslot = lane & 15;
  int asel = (lane & 48);  // bpermute base: source lane group for this head
  const unsigned short* sl = hsl + (size_t)c * N * 128;
  float acc0 = 0.f, acc1 = 0.f;
  int k0 = offsets[n], k1 = offsets[n + 1];
  int nk = k1 - k0;
  int base = 0;
  for (; base + 16 <= nk; base += 16) {
    int kk = k0 + base + lslot;
    int se = esrc[kk];
    float ae = exs[(k0 + base + lslot) * 4 + head];
#pragma unroll
    for (int e = 0; e < 16; ++e) {
      int s = __builtin_amdgcn_readlane(se, e);
      float a = __shfl(ae, asel + e);
      unsigned p = *(const unsigned*)&sl[(size_t)s * 128 + lane * 2];
      acc0 += a * bf_lo(p);
      acc1 += a * bf_hi(p);
    }
  }
  int rem = nk - base;
  if (rem > 0) {
    int kk = k0 + base + lslot;
    int kc = kk < k1 ? kk : k1 - 1;
    int se = esrc[kc];
    float ae = exs[kc * 4 + head];
    for (int e = 0; e < rem; ++e) {
      int s = __builtin_amdgcn_readlane(se, e);
      float a = __shfl(ae, asel + e);
      unsigned p = *(const unsigned*)&sl[(size_t)s * 128 + lane * 2];
      acc0 += a * bf_lo(p);
      acc1 += a * bf_hi(p);
    }
  }
  float ia = inva[n * 4 + head];  // includes 0.25 head-mean
  acc0 *= ia;
  acc1 *= ia;
  acc0 += __shfl_xor(acc0, 16);
  acc0 += __shfl_xor(acc0, 32);
  acc1 += __shfl_xor(acc1, 16);
  acc1 += __shfl_xor(acc1, 32);
  if (lane < 16) {
    int oc = c * 32 + lane * 2;
    float v0 = acc0 + bias[oc];
    float v1 = acc1 + bias[oc + 1];
    if (xout) *(float2*)&xout[(size_t)n * CH + oc] = make_float2(v0, v1);
    if (xout_bf) {
      ushort2 o;
      o.x = f2bf(v0);
      o.y = f2bf(v1);
      *(ushort2*)&xout_bf[(size_t)n * CH + oc] = o;
    }
  }
}

extern "C" void kernel_launch(void* const* d_in, const int* in_sizes, int n_in,
                              void* d_out, int out_size, void* d_ws, size_t ws_size,
                              hipStream_t stream) {
  const float* x = (const float*)d_in[0];
  const int* ei = (const int*)d_in[1];
  const float* W[3] = {(const float*)d_in[2], (const float*)d_in[6], (const float*)d_in[10]};
  const float* AS[3] = {(const float*)d_in[3], (const float*)d_in[7], (const float*)d_in[11]};
  const float* AD[3] = {(const float*)d_in[4], (const float*)d_in[8], (const float*)d_in[12]};
  const float* BI[3] = {(const float*)d_in[5], (const float*)d_in[9], (const float*)d_in[13]};
  const int N = in_sizes[0] / 512;
  const int E = in_sizes[1] / 2;
  const int ET = E + N;
  const int Kd[3] = {512, 256, 256};

  char* p = (char*)d_ws;
  auto alloc = [&](size_t bytes) {
    char* r = p;
    p += (bytes + 255) & ~(size_t)255;
    return (void*)r;
  };
  unsigned short* hsl = (unsigned short*)alloc((size_t)NSLICE * N * 128 * 2);
  unsigned short* axb = (unsigned short*)alloc((size_t)N * 512 * 2);
  unsigned short* actbf = (unsigned short*)alloc((size_t)N * CH * 2);
  unsigned short* Wt[3];
  for (int i = 0; i < 3; i++) Wt[i] = (unsigned short*)alloc((size_t)HC * Kd[i] * 2);
  float* es = (float*)alloc((size_t)N * HEADS * 4);
  float* ed = (float*)alloc((size_t)N * HEADS * 4);
  float* exs = (float*)alloc((size_t)ET * HEADS * 4);
  float* inva = (float*)alloc((size_t)N * HEADS * 4);
  int* offsets = (int*)alloc((size_t)(N + 1) * 4);
  int* cursor = (int*)alloc((size_t)N * 4);
  int* esrc = (int*)alloc((size_t)ET * 4);
  int* edst = (int*)alloc((size_t)ET * 4);

  // ---- CSR build (shared by all 3 layers) ----
  hipMemsetAsync(cursor, 0, (size_t)N * 4, stream);
  k_count<<<cdiv(ET, 256), 256, 0, stream>>>(ei, E, ET, cursor);
  k_scan<<<1, 1024, 0, stream>>>(cursor, offsets, N);
  hipMemsetAsync(cursor, 0, (size_t)N * 4, stream);
  k_fill<<<cdiv(ET, 256), 256, 0, stream>>>(ei, E, ET, offsets, cursor, esrc, edst);

  // ---- weight transpose+cast, input cast ----
  for (int i = 0; i < 3; i++)
    k_transpose_w<<<dim3(Kd[i] / 32, HC / 32), 256, 0, stream>>>(W[i], Wt[i], Kd[i]);
  k_cast_bf16<<<cdiv(N * 512, 8 * 256), 256, 0, stream>>>(x, axb, N * 512);

  const unsigned short* ain = axb;
  int aggGrid = cdiv(N, 4) * 8;
  for (int layer = 0; layer < 3; ++layer) {
    int K = Kd[layer];
    k_gemm_mfma<<<dim3(cdiv(N, 128), HC / 128), 256, 0, stream>>>(ain, Wt[layer], hsl, N, K);
    k_logits<<<N, 256, 0, stream>>>(hsl, AS[layer], AD[layer], es, ed, N);
    k_edge_exp<<<cdiv(ET, 256), 256, 0, stream>>>(esrc, edst, ET, (const float4*)es,
                                                  (const float4*)ed, (float4*)exs);
    k_denom<<<cdiv(N, 4), 256, 0, stream>>>(exs, offsets, inva, N);
    if (layer < 2) {
      k_aggregate<<<aggGrid, 256, 0, stream>>>(hsl, exs, inva, offsets, esrc, BI[layer],
                                               (float*)nullptr, actbf, N);
    } else {
      k_aggregate<<<aggGrid, 256, 0, stream>>>(hsl, exs, inva, offsets, esrc, BI[layer],
                                               (float*)d_out, (unsigned short*)nullptr, N);
    }
    ain = actbf;
  }
}

// Round 8
// 287.445 us; speedup vs baseline: 1.3219x; 1.1269x over previous
//
#include <hip/hip_runtime.h>
#include <math.h>

#define HEADS 4
#define CH 256
#define HC 1024
#define NSLICE 8
#define NEG_SLOPE 0.2f
#define EPSQ 1e-16f

typedef __attribute__((ext_vector_type(8))) short bf16x8;
typedef __attribute__((ext_vector_type(4))) float f32x4;

static inline int cdiv(int a, int b) { return (a + b - 1) / b; }

__device__ __forceinline__ unsigned short f2bf(float f) {
  unsigned u = __float_as_uint(f);
  u += 0x7FFFu + ((u >> 16) & 1u);  // RNE
  return (unsigned short)(u >> 16);
}
__device__ __forceinline__ float bf2f(unsigned short s) {
  return __uint_as_float(((unsigned)s) << 16);
}
__device__ __forceinline__ void gload_lds16(const void* g, void* l) {
  __builtin_amdgcn_global_load_lds((const __attribute__((address_space(1))) void*)g,
                                   (__attribute__((address_space(3))) void*)l, 16, 0, 0);
}

// ---------------- CSR build ----------------
__global__ void k_count(const int* __restrict__ ei, int E, int ET, int* __restrict__ cnt) {
  int e = blockIdx.x * blockDim.x + threadIdx.x;
  if (e >= ET) return;
  int d = (e < E) ? ei[E + e] : (e - E);
  atomicAdd(&cnt[d], 1);
}

__global__ __launch_bounds__(1024) void k_scan(const int* __restrict__ counts,
                                               int* __restrict__ offsets, int n) {
  __shared__ int wsum[16];
  __shared__ int carry_s;
  int lane = threadIdx.x & 63, wv = threadIdx.x >> 6;
  if (threadIdx.x == 0) carry_s = 0;
  __syncthreads();
  for (int base = 0; base < n; base += 1024) {
    int i = base + threadIdx.x;
    int orig = (i < n) ? counts[i] : 0;
    int v = orig;
#pragma unroll
    for (int off = 1; off < 64; off <<= 1) {
      int t = __shfl_up(v, off);
      if (lane >= off) v += t;
    }
    if (lane == 63) wsum[wv] = v;
    __syncthreads();
    int carry = carry_s;
    int wpre = 0;
#pragma unroll
    for (int w = 0; w < 16; w++) wpre += (w < wv) ? wsum[w] : 0;
    int incl = v + wpre;
    if (i < n) offsets[i] = carry + incl - orig;
    __syncthreads();
    if (threadIdx.x == 1023) carry_s = carry + incl;
    __syncthreads();
  }
  if (threadIdx.x == 0) offsets[n] = carry_s;
}

__global__ void k_fill(const int* __restrict__ ei, int E, int ET,
                       const int* __restrict__ offsets, int* __restrict__ cursor,
                       int* __restrict__ esrc, int* __restrict__ edst) {
  int e = blockIdx.x * blockDim.x + threadIdx.x;
  if (e >= ET) return;
  int s = (e < E) ? ei[e] : (e - E);
  int d = (e < E) ? ei[E + e] : (e - E);
  int pos = offsets[d] + atomicAdd(&cursor[d], 1);
  esrc[pos] = s;
  edst[pos] = d;
}

// ---------------- W transpose + cast ----------------
__global__ __launch_bounds__(256) void k_transpose_w(const float* __restrict__ W,
                                                     unsigned short* __restrict__ Wt, int K) {
  __shared__ float tile[32][33];
  int tx = threadIdx.x & 31, ty = threadIdx.x >> 5;
  int k0 = blockIdx.x * 32, n0 = blockIdx.y * 32;
#pragma unroll
  for (int r = ty; r < 32; r += 8) tile[r][tx] = W[(size_t)(k0 + r) * HC + n0 + tx];
  __syncthreads();
#pragma unroll
  for (int r = ty; r < 32; r += 8)
    Wt[(size_t)(n0 + r) * K + k0 + tx] = f2bf(tile[tx][r]);
}

// ---------------- cast fp32 -> bf16 ----------------
__global__ void k_cast_bf16(const float* __restrict__ in, unsigned short* __restrict__ out,
                            int n) {
  int i = (blockIdx.x * blockDim.x + threadIdx.x) * 8;
  if (i >= n) return;
  float4 a = *(const float4*)&in[i];
  float4 b = *(const float4*)&in[i + 4];
  ushort4 lo = make_ushort4(f2bf(a.x), f2bf(a.y), f2bf(a.z), f2bf(a.w));
  ushort4 hi = make_ushort4(f2bf(b.x), f2bf(b.y), f2bf(b.z), f2bf(b.w));
  *(ushort4*)&out[i] = lo;
  *(ushort4*)&out[i + 4] = hi;
}

// ---------------- bf16 MFMA GEMM, epilogue writes slice-major hsl[c][n][128] ----
__global__ __launch_bounds__(256) void k_gemm_mfma(const unsigned short* __restrict__ A,
                                                   const unsigned short* __restrict__ Bt,
                                                   unsigned short* __restrict__ hsl, int M,
                                                   int K) {
  __shared__ unsigned short sA[2][128 * 32];
  __shared__ unsigned short sB[2][128 * 32];
  int t = threadIdx.x;
  int lane = t & 63, wv = t >> 6;
  int wr = wv >> 1, wc = wv & 1;
  int row0 = blockIdx.x * 128, col0 = blockIdx.y * 128;
  int l15 = lane & 15, l4 = lane >> 4;

  f32x4 acc[4][4] = {};

  auto stage = [&](unsigned short* sdst, const unsigned short* g, int grow0, int rowmax,
                   int k0) {
#pragma unroll
    for (int q = 0; q < 2; ++q) {
      int r = grow0 + q * 64 + (t >> 2);
      if (r > rowmax) r = rowmax;
      const unsigned short* gp = g + (size_t)r * K + k0 + (t & 3) * 8;
      gload_lds16(gp, sdst + q * 2048 + t * 8);
    }
  };

  int KT = K / 32;
  stage(sA[0], A, row0, M - 1, 0);
  stage(sB[0], Bt, col0, HC - 1, 0);
  int cur = 0;
  for (int kt = 0; kt < KT; ++kt) {
    __syncthreads();
    if (kt + 1 < KT) {
      stage(sA[cur ^ 1], A, row0, M - 1, (kt + 1) * 32);
      stage(sB[cur ^ 1], Bt, col0, HC - 1, (kt + 1) * 32);
    }
    bf16x8 af[4], bfr[4];
#pragma unroll
    for (int i = 0; i < 4; i++)
      af[i] = *(bf16x8*)&sA[cur][(wr * 64 + i * 16 + l15) * 32 + l4 * 8];
#pragma unroll
    for (int j = 0; j < 4; j++)
      bfr[j] = *(bf16x8*)&sB[cur][(wc * 64 + j * 16 + l15) * 32 + l4 * 8];
#pragma unroll
    for (int i = 0; i < 4; i++)
#pragma unroll
      for (int j = 0; j < 4; j++)
        acc[i][j] = __builtin_amdgcn_mfma_f32_16x16x32_bf16(af[i], bfr[j], acc[i][j], 0, 0, 0);
    cur ^= 1;
  }
#pragma unroll
  for (int i = 0; i < 4; i++) {
#pragma unroll
    for (int j = 0; j < 4; j++) {
      int col = col0 + wc * 64 + j * 16 + l15;
      int head = col >> 8;
      int c = (col >> 5) & 7;
      int jj = col & 31;
      size_t sbase = ((size_t)c * M) * 128 + (head << 5) + jj;
#pragma unroll
      for (int r = 0; r < 4; r++) {
        int row = row0 + wr * 64 + i * 16 + l4 * 4 + r;
        if (row < M) hsl[sbase + (size_t)row * 128] = f2bf(acc[i][j][r]);
      }
    }
  }
}

// ---------------- per-node logits from slice-major hsl ----------------
__global__ __launch_bounds__(256) void k_logits(const unsigned short* __restrict__ hsl,
                                                const float* __restrict__ as_,
                                                const float* __restrict__ ad_,
                                                float* __restrict__ es, float* __restrict__ ed,
                                                int M) {
  __shared__ float lds_s[4][64];
  __shared__ float lds_d[4][64];
  int n = blockIdx.x;
  int t = threadIdx.x;
  int c = t >> 5, chunk = t & 31;
  int head = chunk >> 3, q = chunk * 4;
  ushort4 hv = *(const ushort4*)&hsl[((size_t)c * M + n) * 128 + q];
  int ch = head * 256 + c * 32 + (q & 31);
  float4 s4 = *(const float4*)&as_[ch];
  float4 d4 = *(const float4*)&ad_[ch];
  float h0 = bf2f(hv.x), h1 = bf2f(hv.y), h2 = bf2f(hv.z), h3 = bf2f(hv.w);
  float ds = h0 * s4.x + h1 * s4.y + h2 * s4.z + h3 * s4.w;
  float dd = h0 * d4.x + h1 * d4.y + h2 * d4.z + h3 * d4.w;
  int g = c * 8 + (chunk & 7);
  lds_s[head][g] = ds;
  lds_d[head][g] = dd;
  __syncthreads();
  int wv = t >> 6, l = t & 63;
  float vs = lds_s[wv][l];
  float vd = lds_d[wv][l];
#pragma unroll
  for (int off = 32; off; off >>= 1) {
    vs += __shfl_xor(vs, off);
    vd += __shfl_xor(vd, off);
  }
  if (l == 0) {
    es[n * HEADS + wv] = vs;
    ed[n * HEADS + wv] = vd;
  }
}

// ---------------- slot-ordered edge exp ----------------
__global__ void k_edge_exp(const int* __restrict__ esrc, const int* __restrict__ edst, int ET,
                           const float4* __restrict__ es4, const float4* __restrict__ ed4,
                           float4* __restrict__ exs4) {
  int k = blockIdx.x * blockDim.x + threadIdx.x;
  if (k >= ET) return;
  int s = esrc[k], d = edst[k];
  float4 a = es4[s], b = ed4[d];
  float v0 = a.x + b.x, v1 = a.y + b.y, v2 = a.z + b.z, v3 = a.w + b.w;
  v0 = v0 > 0.f ? v0 : NEG_SLOPE * v0;
  v1 = v1 > 0.f ? v1 : NEG_SLOPE * v1;
  v2 = v2 > 0.f ? v2 : NEG_SLOPE * v2;
  v3 = v3 > 0.f ? v3 : NEG_SLOPE * v3;
  exs4[k] = make_float4(__expf(v0), __expf(v1), __expf(v2), __expf(v3));
}

// ---------------- per-node inverse denom ----------------
__global__ __launch_bounds__(256) void k_denom(const float* __restrict__ exs,
                                               const int* __restrict__ offsets,
                                               float* __restrict__ inva, int N) {
  int lane = threadIdx.x & 63;
  int n = blockIdx.x * 4 + (threadIdx.x >> 6);
  if (n >= N) return;
  int sub = lane >> 2, h = lane & 3;
  int k0 = offsets[n], k1 = offsets[n + 1];
  float sum = 0.f;
  for (int k = k0 + sub; k < k1; k += 16) sum += exs[k * 4 + h];
#pragma unroll
  for (int off = 4; off < 64; off <<= 1) sum += __shfl_xor(sum, off);
  if (lane < 4) inva[n * 4 + h] = 0.25f / (sum + EPSQ);
}

// ---------------- XCD-sliced aggregation, 4 edges per wave ----------------
// Wave = 4 groups of 16 lanes; group g walks edges k0+g, k0+g+4, ...
// Lane (g,q) owns 16B = 8 channels (q*8..q*8+7, head hq=q>>2) of the slice row.
// Per iteration: 2 broadcast dword loads (esrc, exs) + 1 dwordx4 h-load; no
// cross-lane ops inside the loop. Per-head softmax scale (inva, incl. 0.25
// head-mean) applied before the final shfl_xor head-sum + group-sum.
__global__ __launch_bounds__(256) void k_aggregate(const unsigned short* __restrict__ hsl,
                                                   const float* __restrict__ exs,
                                                   const float* __restrict__ inva,
                                                   const int* __restrict__ offsets,
                                                   const int* __restrict__ esrc,
                                                   const float* __restrict__ bias,
                                                   float* __restrict__ xout,
                                                   unsigned short* __restrict__ xout_bf,
                                                   int N) {
  int c = blockIdx.x & 7;
  int n = (blockIdx.x >> 3) * 4 + (threadIdx.x >> 6);
  if (n >= N) return;
  int lane = threadIdx.x & 63;
  int g = lane >> 4;   // edge subgroup
  int q = lane & 15;   // 16B segment within slice row
  int hq = q >> 2;     // head of this segment
  const unsigned short* sl = hsl + (size_t)c * N * 128;
  float acc[8] = {};
  int k0 = offsets[n], k1 = offsets[n + 1];
  int k = k0 + g;
  for (; k + 4 < k1; k += 8) {
    int sA = esrc[k], sB = esrc[k + 4];
    float aA = exs[k * 4 + hq];
    float aB = exs[(k + 4) * 4 + hq];
    bf16x8 vA = *(const bf16x8*)&sl[((size_t)sA << 7) + q * 8];
    bf16x8 vB = *(const bf16x8*)&sl[((size_t)sB << 7) + q * 8];
#pragma unroll
    for (int j = 0; j < 8; j++)
      acc[j] += aA * bf2f((unsigned short)vA[j]) + aB * bf2f((unsigned short)vB[j]);
  }
  if (k < k1) {
    int sA = esrc[k];
    float aA = exs[k * 4 + hq];
    bf16x8 vA = *(const bf16x8*)&sl[((size_t)sA << 7) + q * 8];
#pragma unroll
    for (int j = 0; j < 8; j++) acc[j] += aA * bf2f((unsigned short)vA[j]);
  }
  float ia = inva[n * 4 + hq];  // includes 0.25 head-mean
#pragma unroll
  for (int j = 0; j < 8; j++) {
    float v = acc[j] * ia;
    v += __shfl_xor(v, 16);  // edge groups
    v += __shfl_xor(v, 32);
    v += __shfl_xor(v, 4);   // heads
    v += __shfl_xor(v, 8);
    acc[j] = v;
  }
  if (lane < 4) {  // lane q in 0..3 holds within-head channels q*8..q*8+7, head-summed
    int oc = c * 32 + lane * 8;
    if (xout) {
      float4 o0 = make_float4(acc[0] + bias[oc + 0], acc[1] + bias[oc + 1],
                              acc[2] + bias[oc + 2], acc[3] + bias[oc + 3]);
      float4 o1 = make_float4(acc[4] + bias[oc + 4], acc[5] + bias[oc + 5],
                              acc[6] + bias[oc + 6], acc[7] + bias[oc + 7]);
      *(float4*)&xout[(size_t)n * CH + oc] = o0;
      *(float4*)&xout[(size_t)n * CH + oc + 4] = o1;
    }
    if (xout_bf) {
      ushort4 o0 = make_ushort4(f2bf(acc[0] + bias[oc + 0]), f2bf(acc[1] + bias[oc + 1]),
                                f2bf(acc[2] + bias[oc + 2]), f2bf(acc[3] + bias[oc + 3]));
      ushort4 o1 = make_ushort4(f2bf(acc[4] + bias[oc + 4]), f2bf(acc[5] + bias[oc + 5]),
                                f2bf(acc[6] + bias[oc + 6]), f2bf(acc[7] + bias[oc + 7]));
      *(ushort4*)&xout_bf[(size_t)n * CH + oc] = o0;
      *(ushort4*)&xout_bf[(size_t)n * CH + oc + 4] = o1;
    }
  }
}

extern "C" void kernel_launch(void* const* d_in, const int* in_sizes, int n_in,
                              void* d_out, int out_size, void* d_ws, size_t ws_size,
                              hipStream_t stream) {
  const float* x = (const float*)d_in[0];
  const int* ei = (const int*)d_in[1];
  const float* W[3] = {(const float*)d_in[2], (const float*)d_in[6], (const float*)d_in[10]};
  const float* AS[3] = {(const float*)d_in[3], (const float*)d_in[7], (const float*)d_in[11]};
  const float* AD[3] = {(const float*)d_in[4], (const float*)d_in[8], (const float*)d_in[12]};
  const float* BI[3] = {(const float*)d_in[5], (const float*)d_in[9], (const float*)d_in[13]};
  const int N = in_sizes[0] / 512;
  const int E = in_sizes[1] / 2;
  const int ET = E + N;
  const int Kd[3] = {512, 256, 256};

  char* p = (char*)d_ws;
  auto alloc = [&](size_t bytes) {
    char* r = p;
    p += (bytes + 255) & ~(size_t)255;
    return (void*)r;
  };
  unsigned short* hsl = (unsigned short*)alloc((size_t)NSLICE * N * 128 * 2);
  unsigned short* axb = (unsigned short*)alloc((size_t)N * 512 * 2);
  unsigned short* actbf = (unsigned short*)alloc((size_t)N * CH * 2);
  unsigned short* Wt[3];
  for (int i = 0; i < 3; i++) Wt[i] = (unsigned short*)alloc((size_t)HC * Kd[i] * 2);
  float* es = (float*)alloc((size_t)N * HEADS * 4);
  float* ed = (float*)alloc((size_t)N * HEADS * 4);
  float* exs = (float*)alloc((size_t)ET * HEADS * 4);
  float* inva = (float*)alloc((size_t)N * HEADS * 4);
  int* offsets = (int*)alloc((size_t)(N + 1) * 4);
  int* cursor = (int*)alloc((size_t)N * 4);
  int* esrc = (int*)alloc((size_t)ET * 4);
  int* edst = (int*)alloc((size_t)ET * 4);

  // ---- CSR build (shared by all 3 layers) ----
  hipMemsetAsync(cursor, 0, (size_t)N * 4, stream);
  k_count<<<cdiv(ET, 256), 256, 0, stream>>>(ei, E, ET, cursor);
  k_scan<<<1, 1024, 0, stream>>>(cursor, offsets, N);
  hipMemsetAsync(cursor, 0, (size_t)N * 4, stream);
  k_fill<<<cdiv(ET, 256), 256, 0, stream>>>(ei, E, ET, offsets, cursor, esrc, edst);

  // ---- weight transpose+cast, input cast ----
  for (int i = 0; i < 3; i++)
    k_transpose_w<<<dim3(Kd[i] / 32, HC / 32), 256, 0, stream>>>(W[i], Wt[i], Kd[i]);
  k_cast_bf16<<<cdiv(N * 512, 8 * 256), 256, 0, stream>>>(x, axb, N * 512);

  const unsigned short* ain = axb;
  int aggGrid = cdiv(N, 4) * 8;
  for (int layer = 0; layer < 3; ++layer) {
    int K = Kd[layer];
    k_gemm_mfma<<<dim3(cdiv(N, 128), HC / 128), 256, 0, stream>>>(ain, Wt[layer], hsl, N, K);
    k_logits<<<N, 256, 0, stream>>>(hsl, AS[layer], AD[layer], es, ed, N);
    k_edge_exp<<<cdiv(ET, 256), 256, 0, stream>>>(esrc, edst, ET, (const float4*)es,
                                                  (const float4*)ed, (float4*)exs);
    k_denom<<<cdiv(N, 4), 256, 0, stream>>>(exs, offsets, inva, N);
    if (layer < 2) {
      k_aggregate<<<aggGrid, 256, 0, stream>>>(hsl, exs, inva, offsets, esrc, BI[layer],
                                               (float*)nullptr, actbf, N);
    } else {
      k_aggregate<<<aggGrid, 256, 0, stream>>>(hsl, exs, inva, offsets, esrc, BI[layer],
                                               (float*)d_out, (unsigned short*)nullptr, N);
    }
    ain = actbf;
  }
}